// Round 9
// baseline (172.409 us; speedup 1.0000x reference)
//
#include <hip/hip_runtime.h>
#include <math.h>

#define NB 64
#define NC 512
#define NT 1000
#define NH 512
#define TWOC 1024
#define NT4 250   // NT/4 float4 per row
#define TAIL 58   // 250 - 192

typedef float vfloat4 __attribute__((ext_vector_type(4)));

#define GLOAD(dst, addr)        asm volatile("global_load_dwordx4 %0, %1, off"             : "=v"(dst) : "v"(addr))
#define GLOAD_OFF(dst, addr, o) asm volatile("global_load_dwordx4 %0, %1, off offset:" #o  : "=v"(dst) : "v"(addr))

// ---------------- Kernel 1: per-(b,c) mean/std of xs = x0+x1+x2 ----------------
// One wave per row. The 12 float4 loads are inline-asm global_load_dwordx4 so
// the compiler CANNOT recycle result registers / interleave waits (R2-R8: every
// plain-HIP batching collapsed to 28-60 VGPR, ~2 lines in flight, 3.4 TB/s
// latency wall). One explicit vmcnt(0) + sched_barrier before the consume.
__global__ __launch_bounds__(256, 1) void stats_kernel(const float* __restrict__ x0,
                                                       const float* __restrict__ x1,
                                                       const float* __restrict__ x2,
                                                       float* __restrict__ stats) {
    const int row  = blockIdx.x * 4 + (threadIdx.x >> 6);   // 0..32767 ascending
    const int lane = threadIdx.x & 63;

    const float4* p0 = (const float4*)x0 + (size_t)row * NT4;
    const float4* p1 = (const float4*)x1 + (size_t)row * NT4;
    const float4* p2 = (const float4*)x2 + (size_t)row * NT4;

    const bool tail = lane < TAIL;
    const int  i3   = tail ? (192 + lane) : lane;   // safe clamped index
    const float m3  = tail ? 1.f : 0.f;

    const unsigned long long A  = (unsigned long long)(p0 + lane);
    const unsigned long long At = (unsigned long long)(p0 + i3);
    const unsigned long long B  = (unsigned long long)(p1 + lane);
    const unsigned long long Bt = (unsigned long long)(p1 + i3);
    const unsigned long long C  = (unsigned long long)(p2 + lane);
    const unsigned long long Ct = (unsigned long long)(p2 + i3);

    vfloat4 a0, a1, a2, a3, b0, b1, b2, b3, c0, c1, c2, c3;
    GLOAD(a0, A);
    GLOAD_OFF(a1, A, 1024);   // +64 float4
    GLOAD_OFF(a2, A, 2048);   // +128 float4
    GLOAD(a3, At);
    GLOAD(b0, B);
    GLOAD_OFF(b1, B, 1024);
    GLOAD_OFF(b2, B, 2048);
    GLOAD(b3, Bt);
    GLOAD(c0, C);
    GLOAD_OFF(c1, C, 1024);
    GLOAD_OFF(c2, C, 2048);
    GLOAD(c3, Ct);
    asm volatile("s_waitcnt vmcnt(0)" ::: "memory");
    __builtin_amdgcn_sched_barrier(0);   // consumers may not hoist above the wait

    float s0 = 0.f, q0 = 0.f, s1 = 0.f, q1 = 0.f;
    float s2 = 0.f, q2 = 0.f, s3 = 0.f, q3 = 0.f;
    float v;
    v = a0.x + b0.x + c0.x; s0 += v; q0 += v * v;
    v = a0.y + b0.y + c0.y; s0 += v; q0 += v * v;
    v = a0.z + b0.z + c0.z; s0 += v; q0 += v * v;
    v = a0.w + b0.w + c0.w; s0 += v; q0 += v * v;
    v = a1.x + b1.x + c1.x; s1 += v; q1 += v * v;
    v = a1.y + b1.y + c1.y; s1 += v; q1 += v * v;
    v = a1.z + b1.z + c1.z; s1 += v; q1 += v * v;
    v = a1.w + b1.w + c1.w; s1 += v; q1 += v * v;
    v = a2.x + b2.x + c2.x; s2 += v; q2 += v * v;
    v = a2.y + b2.y + c2.y; s2 += v; q2 += v * v;
    v = a2.z + b2.z + c2.z; s2 += v; q2 += v * v;
    v = a2.w + b2.w + c2.w; s2 += v; q2 += v * v;
    v = (a3.x + b3.x + c3.x) * m3; s3 += v; q3 += v * v;
    v = (a3.y + b3.y + c3.y) * m3; s3 += v; q3 += v * v;
    v = (a3.z + b3.z + c3.z) * m3; s3 += v; q3 += v * v;
    v = (a3.w + b3.w + c3.w) * m3; s3 += v; q3 += v * v;

    float s  = (s0 + s1) + (s2 + s3);
    float sq = (q0 + q1) + (q2 + q3);

    #pragma unroll
    for (int off = 32; off; off >>= 1) {
        s  += __shfl_down(s,  off);
        sq += __shfl_down(sq, off);
    }
    if (lane == 0) {
        const float mean = s / (float)NT;
        const float var  = (sq - s * s / (float)NT) / (float)(NT - 1);
        const float sd   = sqrtf(fmaxf(var, 0.f));
        const int b = row >> 9;
        const int c = row & (NC - 1);
        stats[b * TWOC + c]      = mean;
        stats[b * TWOC + NC + c] = sd;
    }
}

// ---------------- Kernel 2a: h[b][j] = dot(stats[b,:], W1[j,:]) + b1[j] ----------------
__global__ __launch_bounds__(256) void h_kernel(const float* __restrict__ stats,
                                                const float* __restrict__ W1,
                                                const float* __restrict__ b1,
                                                float* __restrict__ hbuf) {
    const int wid  = blockIdx.x * 4 + (threadIdx.x >> 6);  // 0..8191
    const int lane = threadIdx.x & 63;
    const int j    = wid >> 4;          // 0..511
    const int b0   = (wid & 15) * 4;    // 0,4,...,60

    const float4* wr  = (const float4*)(W1 + (size_t)j * TWOC);  // 256 float4
    const float4* s0p = (const float4*)(stats + (size_t)(b0 + 0) * TWOC);
    const float4* s1p = (const float4*)(stats + (size_t)(b0 + 1) * TWOC);
    const float4* s2p = (const float4*)(stats + (size_t)(b0 + 2) * TWOC);
    const float4* s3p = (const float4*)(stats + (size_t)(b0 + 3) * TWOC);

    float a0 = 0.f, a1 = 0.f, a2 = 0.f, a3 = 0.f;
    #pragma unroll
    for (int r = 0; r < 4; ++r) {
        const int i4 = r * 64 + lane;
        const float4 wv = wr[i4];
        const float4 v0 = s0p[i4];
        const float4 v1 = s1p[i4];
        const float4 v2 = s2p[i4];
        const float4 v3 = s3p[i4];
        a0 += wv.x*v0.x + wv.y*v0.y + wv.z*v0.z + wv.w*v0.w;
        a1 += wv.x*v1.x + wv.y*v1.y + wv.z*v1.z + wv.w*v1.w;
        a2 += wv.x*v2.x + wv.y*v2.y + wv.z*v2.z + wv.w*v2.w;
        a3 += wv.x*v3.x + wv.y*v3.y + wv.z*v3.z + wv.w*v3.w;
    }
    #pragma unroll
    for (int off = 32; off; off >>= 1) {
        a0 += __shfl_down(a0, off);
        a1 += __shfl_down(a1, off);
        a2 += __shfl_down(a2, off);
        a3 += __shfl_down(a3, off);
    }
    if (lane == 0) {
        const float bb = b1[j];
        hbuf[(size_t)(b0 + 0) * NH + j] = a0 + bb;
        hbuf[(size_t)(b0 + 1) * NH + j] = a1 + bb;
        hbuf[(size_t)(b0 + 2) * NH + j] = a2 + bb;
        hbuf[(size_t)(b0 + 3) * NH + j] = a3 + bb;
    }
}

// ---------------- Kernel 2b: s[b,k,c] = dot(h[b,:], W2[k,c,:]) + b2[k,c]; w = softmax_k ----------------
__global__ __launch_bounds__(256) void sw_kernel(const float* __restrict__ hbuf,
                                                 const float* __restrict__ W2,
                                                 const float* __restrict__ b2,
                                                 float* __restrict__ wbuf) {
    const int wid  = blockIdx.x * 4 + (threadIdx.x >> 6);  // 0..8191
    const int lane = threadIdx.x & 63;
    const int c    = wid >> 4;          // 0..511
    const int b0   = (wid & 15) * 4;

    const float4* w0r = (const float4*)(W2 + ((size_t)(0 * NC + c)) * NH);  // 128 float4
    const float4* w1r = (const float4*)(W2 + ((size_t)(1 * NC + c)) * NH);
    const float4* w2r = (const float4*)(W2 + ((size_t)(2 * NC + c)) * NH);

    float acc00=0,acc01=0,acc02=0,acc03=0;
    float acc10=0,acc11=0,acc12=0,acc13=0;
    float acc20=0,acc21=0,acc22=0,acc23=0;

    #pragma unroll
    for (int r = 0; r < 2; ++r) {
        const int i4 = r * 64 + lane;
        const float4 w0v = w0r[i4];
        const float4 w1v = w1r[i4];
        const float4 w2v = w2r[i4];
        const float4 h0 = ((const float4*)(hbuf + (size_t)(b0 + 0) * NH))[i4];
        const float4 h1 = ((const float4*)(hbuf + (size_t)(b0 + 1) * NH))[i4];
        const float4 h2 = ((const float4*)(hbuf + (size_t)(b0 + 2) * NH))[i4];
        const float4 h3 = ((const float4*)(hbuf + (size_t)(b0 + 3) * NH))[i4];
        acc00 += w0v.x*h0.x + w0v.y*h0.y + w0v.z*h0.z + w0v.w*h0.w;
        acc01 += w0v.x*h1.x + w0v.y*h1.y + w0v.z*h1.z + w0v.w*h1.w;
        acc02 += w0v.x*h2.x + w0v.y*h2.y + w0v.z*h2.z + w0v.w*h2.w;
        acc03 += w0v.x*h3.x + w0v.y*h3.y + w0v.z*h3.z + w0v.w*h3.w;
        acc10 += w1v.x*h0.x + w1v.y*h0.y + w1v.z*h0.z + w1v.w*h0.w;
        acc11 += w1v.x*h1.x + w1v.y*h1.y + w1v.z*h1.z + w1v.w*h1.w;
        acc12 += w1v.x*h2.x + w1v.y*h2.y + w1v.z*h2.z + w1v.w*h2.w;
        acc13 += w1v.x*h3.x + w1v.y*h3.y + w1v.z*h3.z + w1v.w*h3.w;
        acc20 += w2v.x*h0.x + w2v.y*h0.y + w2v.z*h0.z + w2v.w*h0.w;
        acc21 += w2v.x*h1.x + w2v.y*h1.y + w2v.z*h1.z + w2v.w*h1.w;
        acc22 += w2v.x*h2.x + w2v.y*h2.y + w2v.z*h2.z + w2v.w*h2.w;
        acc23 += w2v.x*h3.x + w2v.y*h3.y + w2v.z*h3.z + w2v.w*h3.w;
    }
    #pragma unroll
    for (int off = 32; off; off >>= 1) {
        acc00 += __shfl_down(acc00, off); acc01 += __shfl_down(acc01, off);
        acc02 += __shfl_down(acc02, off); acc03 += __shfl_down(acc03, off);
        acc10 += __shfl_down(acc10, off); acc11 += __shfl_down(acc11, off);
        acc12 += __shfl_down(acc12, off); acc13 += __shfl_down(acc13, off);
        acc20 += __shfl_down(acc20, off); acc21 += __shfl_down(acc21, off);
        acc22 += __shfl_down(acc22, off); acc23 += __shfl_down(acc23, off);
    }
    if (lane == 0) {
        const float bb0 = b2[0 * NC + c];
        const float bb1 = b2[1 * NC + c];
        const float bb2 = b2[2 * NC + c];
        float v0[4] = {acc00 + bb0, acc01 + bb0, acc02 + bb0, acc03 + bb0};
        float v1[4] = {acc10 + bb1, acc11 + bb1, acc12 + bb1, acc13 + bb1};
        float v2[4] = {acc20 + bb2, acc21 + bb2, acc22 + bb2, acc23 + bb2};
        #pragma unroll
        for (int bb = 0; bb < 4; ++bb) {
            const float m  = fmaxf(v0[bb], fmaxf(v1[bb], v2[bb]));
            const float e0 = expf(v0[bb] - m);
            const float e1 = expf(v1[bb] - m);
            const float e2 = expf(v2[bb] - m);
            const float inv = 1.f / (e0 + e1 + e2);
            const size_t base = (size_t)(b0 + bb) * 3 * NC + c;
            wbuf[base + 0 * NC] = e0 * inv;
            wbuf[base + 1 * NC] = e1 * inv;
            wbuf[base + 2 * NC] = e2 * inv;
        }
    }
}

// ---------------- Kernel 3: out = w0*x0 + w1*x1 + w2*x2 ----------------
// Descending row order (boustrophedon vs stats); NT stores (out never re-read).
__global__ __launch_bounds__(256) void apply_kernel(const float* __restrict__ x0,
                                                    const float* __restrict__ x1,
                                                    const float* __restrict__ x2,
                                                    const float* __restrict__ wbuf,
                                                    float* __restrict__ out) {
    const int rblk = (int)gridDim.x - 1 - (int)blockIdx.x;     // reverse block order
    const int row  = rblk * 4 + (threadIdx.x >> 6);
    const int lane = threadIdx.x & 63;
    const int b = row >> 9;
    const int c = row & (NC - 1);

    const float4* p0 = (const float4*)x0 + (size_t)row * NT4;
    const float4* p1 = (const float4*)x1 + (size_t)row * NT4;
    const float4* p2 = (const float4*)x2 + (size_t)row * NT4;
    vfloat4*      po = (vfloat4*)out     + (size_t)row * NT4;

    const bool tail = lane < TAIL;
    const int  i3   = tail ? (192 + lane) : lane;

    const float w0 = wbuf[((size_t)b * 3 + 0) * NC + c];
    const float w1 = wbuf[((size_t)b * 3 + 1) * NC + c];
    const float w2 = wbuf[((size_t)b * 3 + 2) * NC + c];
    const float4 a0 = p0[lane];
    const float4 a1 = p0[lane + 64];
    const float4 a2 = p0[lane + 128];
    const float4 a3 = p0[i3];
    const float4 d0 = p1[lane];
    const float4 d1 = p1[lane + 64];
    const float4 d2 = p1[lane + 128];
    const float4 d3 = p1[i3];
    const float4 e0 = p2[lane];
    const float4 e1 = p2[lane + 64];
    const float4 e2 = p2[lane + 128];
    const float4 e3 = p2[i3];
    __builtin_amdgcn_sched_barrier(0);

    vfloat4 o;
    o.x = a0.x*w0 + d0.x*w1 + e0.x*w2;
    o.y = a0.y*w0 + d0.y*w1 + e0.y*w2;
    o.z = a0.z*w0 + d0.z*w1 + e0.z*w2;
    o.w = a0.w*w0 + d0.w*w1 + e0.w*w2;
    __builtin_nontemporal_store(o, &po[lane]);
    o.x = a1.x*w0 + d1.x*w1 + e1.x*w2;
    o.y = a1.y*w0 + d1.y*w1 + e1.y*w2;
    o.z = a1.z*w0 + d1.z*w1 + e1.z*w2;
    o.w = a1.w*w0 + d1.w*w1 + e1.w*w2;
    __builtin_nontemporal_store(o, &po[lane + 64]);
    o.x = a2.x*w0 + d2.x*w1 + e2.x*w2;
    o.y = a2.y*w0 + d2.y*w1 + e2.y*w2;
    o.z = a2.z*w0 + d2.z*w1 + e2.z*w2;
    o.w = a2.w*w0 + d2.w*w1 + e2.w*w2;
    __builtin_nontemporal_store(o, &po[lane + 128]);
    if (tail) {
        o.x = a3.x*w0 + d3.x*w1 + e3.x*w2;
        o.y = a3.y*w0 + d3.y*w1 + e3.y*w2;
        o.z = a3.z*w0 + d3.z*w1 + e3.z*w2;
        o.w = a3.w*w0 + d3.w*w1 + e3.w*w2;
        __builtin_nontemporal_store(o, &po[i3]);
    }
}

extern "C" void kernel_launch(void* const* d_in, const int* in_sizes, int n_in,
                              void* d_out, int out_size, void* d_ws, size_t ws_size,
                              hipStream_t stream) {
    const float* x0 = (const float*)d_in[0];
    const float* x1 = (const float*)d_in[1];
    const float* x2 = (const float*)d_in[2];
    const float* W1 = (const float*)d_in[3];
    const float* b1 = (const float*)d_in[4];
    const float* W2 = (const float*)d_in[5];
    const float* b2 = (const float*)d_in[6];
    float* out = (float*)d_out;

    float* stats = (float*)d_ws;                 // NB*TWOC floats
    float* hbuf  = stats + NB * TWOC;            // NB*NH floats
    float* wbuf  = hbuf + NB * NH;               // NB*3*NC floats

    stats_kernel<<<NB * NC / 4, 256, 0, stream>>>(x0, x1, x2, stats);
    h_kernel<<<2048, 256, 0, stream>>>(stats, W1, b1, hbuf);
    sw_kernel<<<2048, 256, 0, stream>>>(hbuf, W2, b2, wbuf);
    apply_kernel<<<NB * NC / 4, 256, 0, stream>>>(x0, x1, x2, wbuf, out);
}

// Round 10
// 168.465 us; speedup vs baseline: 1.0234x; 1.0234x over previous
//
#include <hip/hip_runtime.h>
#include <math.h>

#define NB 64
#define NC 512
#define NT 1000
#define NH 512
#define TWOC 1024
#define NT4 250   // NT/4 float4 per row
#define TAIL 58   // 250 - 192
#define SWAVES 4096  // persistent stats waves; 8 rows each

typedef float vfloat4 __attribute__((ext_vector_type(4)));

#define GLOAD(dst, addr)          asm volatile("global_load_dwordx4 %0, %1, off"            : "=v"(dst) : "v"(addr))
#define GLOAD_OFF(dst, addr, o)   asm volatile("global_load_dwordx4 %0, %1, off offset:" #o : "=v"(dst) : "v"(addr))
#define VMWAIT(n)                 do { asm volatile("s_waitcnt vmcnt(" #n ")" ::: "memory"); __builtin_amdgcn_sched_barrier(0); } while (0)

// ---------------- Kernel 1: per-(b,c) mean/std of xs = x0+x1+x2 ----------------
// Persistent waves, 8 rows/wave, 2-deep counted-vmcnt pipeline (inline asm).
// R9 proved batched loads + drain-to-zero still pins at 3.4 TB/s: the drain
// empties each wave's request stream every row. Here vmcnt(12) keeps the next
// row's 12 loads in flight across every reduce -- continuous issue per slot.
__global__ __launch_bounds__(256, 1) void stats_kernel(const float* __restrict__ x0f,
                                                       const float* __restrict__ x1f,
                                                       const float* __restrict__ x2f,
                                                       float* __restrict__ stats) {
    const int w    = blockIdx.x * 4 + (threadIdx.x >> 6);   // 0..4095
    const int lane = threadIdx.x & 63;
    const bool tail = lane < TAIL;
    const int  i3   = tail ? (192 + lane) : lane;
    const float m3  = tail ? 1.f : 0.f;

    const float4* x0 = (const float4*)x0f;
    const float4* x1 = (const float4*)x1f;
    const float4* x2 = (const float4*)x2f;

    vfloat4 A0,A1,A2,A3,A4,A5,A6,A7,A8,A9,A10,A11;   // buffer A
    vfloat4 B0,B1,B2,B3,B4,B5,B6,B7,B8,B9,B10,B11;   // buffer B

#define ISSUE(row, R0,R1,R2,R3,R4,R5,R6,R7,R8,R9,R10,R11) do {                     \
        const float4* p0_ = x0 + (size_t)(row) * NT4;                              \
        const float4* p1_ = x1 + (size_t)(row) * NT4;                              \
        const float4* p2_ = x2 + (size_t)(row) * NT4;                              \
        const unsigned long long Aa = (unsigned long long)(p0_ + lane);            \
        const unsigned long long At = (unsigned long long)(p0_ + i3);              \
        const unsigned long long Ba = (unsigned long long)(p1_ + lane);            \
        const unsigned long long Bt = (unsigned long long)(p1_ + i3);              \
        const unsigned long long Ca = (unsigned long long)(p2_ + lane);            \
        const unsigned long long Ct = (unsigned long long)(p2_ + i3);              \
        GLOAD(R0, Aa); GLOAD_OFF(R1, Aa, 1024); GLOAD_OFF(R2, Aa, 2048); GLOAD(R3, At); \
        GLOAD(R4, Ba); GLOAD_OFF(R5, Ba, 1024); GLOAD_OFF(R6, Ba, 2048); GLOAD(R7, Bt); \
        GLOAD(R8, Ca); GLOAD_OFF(R9, Ca, 1024); GLOAD_OFF(R10, Ca, 2048); GLOAD(R11, Ct); \
    } while (0)

#define REDUCE(row, R0,R1,R2,R3,R4,R5,R6,R7,R8,R9,R10,R11) do {                    \
        float s0=0.f,q0=0.f,s1=0.f,q1=0.f,s2=0.f,q2=0.f,s3=0.f,q3=0.f,v;           \
        v = R0.x + R4.x + R8.x;  s0 += v; q0 += v*v;                               \
        v = R0.y + R4.y + R8.y;  s0 += v; q0 += v*v;                               \
        v = R0.z + R4.z + R8.z;  s0 += v; q0 += v*v;                               \
        v = R0.w + R4.w + R8.w;  s0 += v; q0 += v*v;                               \
        v = R1.x + R5.x + R9.x;  s1 += v; q1 += v*v;                               \
        v = R1.y + R5.y + R9.y;  s1 += v; q1 += v*v;                               \
        v = R1.z + R5.z + R9.z;  s1 += v; q1 += v*v;                               \
        v = R1.w + R5.w + R9.w;  s1 += v; q1 += v*v;                               \
        v = R2.x + R6.x + R10.x; s2 += v; q2 += v*v;                               \
        v = R2.y + R6.y + R10.y; s2 += v; q2 += v*v;                               \
        v = R2.z + R6.z + R10.z; s2 += v; q2 += v*v;                               \
        v = R2.w + R6.w + R10.w; s2 += v; q2 += v*v;                               \
        v = (R3.x + R7.x + R11.x) * m3; s3 += v; q3 += v*v;                        \
        v = (R3.y + R7.y + R11.y) * m3; s3 += v; q3 += v*v;                        \
        v = (R3.z + R7.z + R11.z) * m3; s3 += v; q3 += v*v;                        \
        v = (R3.w + R7.w + R11.w) * m3; s3 += v; q3 += v*v;                        \
        float s  = (s0 + s1) + (s2 + s3);                                          \
        float sq = (q0 + q1) + (q2 + q3);                                          \
        _Pragma("unroll")                                                          \
        for (int off = 32; off; off >>= 1) {                                       \
            s  += __shfl_down(s,  off);                                            \
            sq += __shfl_down(sq, off);                                            \
        }                                                                          \
        if (lane == 0) {                                                           \
            const float mean = s / (float)NT;                                      \
            const float var  = (sq - s * s / (float)NT) / (float)(NT - 1);         \
            const float sd   = sqrtf(fmaxf(var, 0.f));                             \
            const int b_ = (row) >> 9;                                             \
            const int c_ = (row) & (NC - 1);                                       \
            stats[b_ * TWOC + c_]      = mean;                                     \
            stats[b_ * TWOC + NC + c_] = sd;                                       \
        }                                                                          \
    } while (0)

    // rows: w + k*SWAVES, k = 0..7
    ISSUE(w, A0,A1,A2,A3,A4,A5,A6,A7,A8,A9,A10,A11);
    ISSUE(w + 1*SWAVES, B0,B1,B2,B3,B4,B5,B6,B7,B8,B9,B10,B11);
    VMWAIT(12);
    REDUCE(w, A0,A1,A2,A3,A4,A5,A6,A7,A8,A9,A10,A11);
    ISSUE(w + 2*SWAVES, A0,A1,A2,A3,A4,A5,A6,A7,A8,A9,A10,A11);
    VMWAIT(12);
    REDUCE(w + 1*SWAVES, B0,B1,B2,B3,B4,B5,B6,B7,B8,B9,B10,B11);
    ISSUE(w + 3*SWAVES, B0,B1,B2,B3,B4,B5,B6,B7,B8,B9,B10,B11);
    VMWAIT(12);
    REDUCE(w + 2*SWAVES, A0,A1,A2,A3,A4,A5,A6,A7,A8,A9,A10,A11);
    ISSUE(w + 4*SWAVES, A0,A1,A2,A3,A4,A5,A6,A7,A8,A9,A10,A11);
    VMWAIT(12);
    REDUCE(w + 3*SWAVES, B0,B1,B2,B3,B4,B5,B6,B7,B8,B9,B10,B11);
    ISSUE(w + 5*SWAVES, B0,B1,B2,B3,B4,B5,B6,B7,B8,B9,B10,B11);
    VMWAIT(12);
    REDUCE(w + 4*SWAVES, A0,A1,A2,A3,A4,A5,A6,A7,A8,A9,A10,A11);
    ISSUE(w + 6*SWAVES, A0,A1,A2,A3,A4,A5,A6,A7,A8,A9,A10,A11);
    VMWAIT(12);
    REDUCE(w + 5*SWAVES, B0,B1,B2,B3,B4,B5,B6,B7,B8,B9,B10,B11);
    ISSUE(w + 7*SWAVES, B0,B1,B2,B3,B4,B5,B6,B7,B8,B9,B10,B11);
    VMWAIT(12);
    REDUCE(w + 6*SWAVES, A0,A1,A2,A3,A4,A5,A6,A7,A8,A9,A10,A11);
    VMWAIT(0);
    REDUCE(w + 7*SWAVES, B0,B1,B2,B3,B4,B5,B6,B7,B8,B9,B10,B11);

#undef ISSUE
#undef REDUCE
}

// ---------------- Kernel 2a: h[b][j] = dot(stats[b,:], W1[j,:]) + b1[j] ----------------
__global__ __launch_bounds__(256) void h_kernel(const float* __restrict__ stats,
                                                const float* __restrict__ W1,
                                                const float* __restrict__ b1,
                                                float* __restrict__ hbuf) {
    const int wid  = blockIdx.x * 4 + (threadIdx.x >> 6);  // 0..8191
    const int lane = threadIdx.x & 63;
    const int j    = wid >> 4;          // 0..511
    const int b0   = (wid & 15) * 4;    // 0,4,...,60

    const float4* wr  = (const float4*)(W1 + (size_t)j * TWOC);  // 256 float4
    const float4* s0p = (const float4*)(stats + (size_t)(b0 + 0) * TWOC);
    const float4* s1p = (const float4*)(stats + (size_t)(b0 + 1) * TWOC);
    const float4* s2p = (const float4*)(stats + (size_t)(b0 + 2) * TWOC);
    const float4* s3p = (const float4*)(stats + (size_t)(b0 + 3) * TWOC);

    float a0 = 0.f, a1 = 0.f, a2 = 0.f, a3 = 0.f;
    #pragma unroll
    for (int r = 0; r < 4; ++r) {
        const int i4 = r * 64 + lane;
        const float4 wv = wr[i4];
        const float4 v0 = s0p[i4];
        const float4 v1 = s1p[i4];
        const float4 v2 = s2p[i4];
        const float4 v3 = s3p[i4];
        a0 += wv.x*v0.x + wv.y*v0.y + wv.z*v0.z + wv.w*v0.w;
        a1 += wv.x*v1.x + wv.y*v1.y + wv.z*v1.z + wv.w*v1.w;
        a2 += wv.x*v2.x + wv.y*v2.y + wv.z*v2.z + wv.w*v2.w;
        a3 += wv.x*v3.x + wv.y*v3.y + wv.z*v3.z + wv.w*v3.w;
    }
    #pragma unroll
    for (int off = 32; off; off >>= 1) {
        a0 += __shfl_down(a0, off);
        a1 += __shfl_down(a1, off);
        a2 += __shfl_down(a2, off);
        a3 += __shfl_down(a3, off);
    }
    if (lane == 0) {
        const float bb = b1[j];
        hbuf[(size_t)(b0 + 0) * NH + j] = a0 + bb;
        hbuf[(size_t)(b0 + 1) * NH + j] = a1 + bb;
        hbuf[(size_t)(b0 + 2) * NH + j] = a2 + bb;
        hbuf[(size_t)(b0 + 3) * NH + j] = a3 + bb;
    }
}

// ---------------- Kernel 2b: s[b,k,c] = dot(h[b,:], W2[k,c,:]) + b2[k,c]; w = softmax_k ----------------
__global__ __launch_bounds__(256) void sw_kernel(const float* __restrict__ hbuf,
                                                 const float* __restrict__ W2,
                                                 const float* __restrict__ b2,
                                                 float* __restrict__ wbuf) {
    const int wid  = blockIdx.x * 4 + (threadIdx.x >> 6);  // 0..8191
    const int lane = threadIdx.x & 63;
    const int c    = wid >> 4;          // 0..511
    const int b0   = (wid & 15) * 4;

    const float4* w0r = (const float4*)(W2 + ((size_t)(0 * NC + c)) * NH);  // 128 float4
    const float4* w1r = (const float4*)(W2 + ((size_t)(1 * NC + c)) * NH);
    const float4* w2r = (const float4*)(W2 + ((size_t)(2 * NC + c)) * NH);

    float acc00=0,acc01=0,acc02=0,acc03=0;
    float acc10=0,acc11=0,acc12=0,acc13=0;
    float acc20=0,acc21=0,acc22=0,acc23=0;

    #pragma unroll
    for (int r = 0; r < 2; ++r) {
        const int i4 = r * 64 + lane;
        const float4 w0v = w0r[i4];
        const float4 w1v = w1r[i4];
        const float4 w2v = w2r[i4];
        const float4 h0 = ((const float4*)(hbuf + (size_t)(b0 + 0) * NH))[i4];
        const float4 h1 = ((const float4*)(hbuf + (size_t)(b0 + 1) * NH))[i4];
        const float4 h2 = ((const float4*)(hbuf + (size_t)(b0 + 2) * NH))[i4];
        const float4 h3 = ((const float4*)(hbuf + (size_t)(b0 + 3) * NH))[i4];
        acc00 += w0v.x*h0.x + w0v.y*h0.y + w0v.z*h0.z + w0v.w*h0.w;
        acc01 += w0v.x*h1.x + w0v.y*h1.y + w0v.z*h1.z + w0v.w*h1.w;
        acc02 += w0v.x*h2.x + w0v.y*h2.y + w0v.z*h2.z + w0v.w*h2.w;
        acc03 += w0v.x*h3.x + w0v.y*h3.y + w0v.z*h3.z + w0v.w*h3.w;
        acc10 += w1v.x*h0.x + w1v.y*h0.y + w1v.z*h0.z + w1v.w*h0.w;
        acc11 += w1v.x*h1.x + w1v.y*h1.y + w1v.z*h1.z + w1v.w*h1.w;
        acc12 += w1v.x*h2.x + w1v.y*h2.y + w1v.z*h2.z + w1v.w*h2.w;
        acc13 += w1v.x*h3.x + w1v.y*h3.y + w1v.z*h3.z + w1v.w*h3.w;
        acc20 += w2v.x*h0.x + w2v.y*h0.y + w2v.z*h0.z + w2v.w*h0.w;
        acc21 += w2v.x*h1.x + w2v.y*h1.y + w2v.z*h1.z + w2v.w*h1.w;
        acc22 += w2v.x*h2.x + w2v.y*h2.y + w2v.z*h2.z + w2v.w*h2.w;
        acc23 += w2v.x*h3.x + w2v.y*h3.y + w2v.z*h3.z + w2v.w*h3.w;
    }
    #pragma unroll
    for (int off = 32; off; off >>= 1) {
        acc00 += __shfl_down(acc00, off); acc01 += __shfl_down(acc01, off);
        acc02 += __shfl_down(acc02, off); acc03 += __shfl_down(acc03, off);
        acc10 += __shfl_down(acc10, off); acc11 += __shfl_down(acc11, off);
        acc12 += __shfl_down(acc12, off); acc13 += __shfl_down(acc13, off);
        acc20 += __shfl_down(acc20, off); acc21 += __shfl_down(acc21, off);
        acc22 += __shfl_down(acc22, off); acc23 += __shfl_down(acc23, off);
    }
    if (lane == 0) {
        const float bb0 = b2[0 * NC + c];
        const float bb1 = b2[1 * NC + c];
        const float bb2 = b2[2 * NC + c];
        float v0[4] = {acc00 + bb0, acc01 + bb0, acc02 + bb0, acc03 + bb0};
        float v1[4] = {acc10 + bb1, acc11 + bb1, acc12 + bb1, acc13 + bb1};
        float v2[4] = {acc20 + bb2, acc21 + bb2, acc22 + bb2, acc23 + bb2};
        #pragma unroll
        for (int bb = 0; bb < 4; ++bb) {
            const float m  = fmaxf(v0[bb], fmaxf(v1[bb], v2[bb]));
            const float e0 = expf(v0[bb] - m);
            const float e1 = expf(v1[bb] - m);
            const float e2 = expf(v2[bb] - m);
            const float inv = 1.f / (e0 + e1 + e2);
            const size_t base = (size_t)(b0 + bb) * 3 * NC + c;
            wbuf[base + 0 * NC] = e0 * inv;
            wbuf[base + 1 * NC] = e1 * inv;
            wbuf[base + 2 * NC] = e2 * inv;
        }
    }
}

// ---------------- Kernel 3: out = w0*x0 + w1*x1 + w2*x2 ----------------
// Descending row order (boustrophedon vs stats); NT stores (out never re-read).
__global__ __launch_bounds__(256) void apply_kernel(const float* __restrict__ x0,
                                                    const float* __restrict__ x1,
                                                    const float* __restrict__ x2,
                                                    const float* __restrict__ wbuf,
                                                    float* __restrict__ out) {
    const int rblk = (int)gridDim.x - 1 - (int)blockIdx.x;     // reverse block order
    const int row  = rblk * 4 + (threadIdx.x >> 6);
    const int lane = threadIdx.x & 63;
    const int b = row >> 9;
    const int c = row & (NC - 1);

    const float4* p0 = (const float4*)x0 + (size_t)row * NT4;
    const float4* p1 = (const float4*)x1 + (size_t)row * NT4;
    const float4* p2 = (const float4*)x2 + (size_t)row * NT4;
    vfloat4*      po = (vfloat4*)out     + (size_t)row * NT4;

    const bool tail = lane < TAIL;
    const int  i3   = tail ? (192 + lane) : lane;

    const float w0 = wbuf[((size_t)b * 3 + 0) * NC + c];
    const float w1 = wbuf[((size_t)b * 3 + 1) * NC + c];
    const float w2 = wbuf[((size_t)b * 3 + 2) * NC + c];
    const float4 a0 = p0[lane];
    const float4 a1 = p0[lane + 64];
    const float4 a2 = p0[lane + 128];
    const float4 a3 = p0[i3];
    const float4 d0 = p1[lane];
    const float4 d1 = p1[lane + 64];
    const float4 d2 = p1[lane + 128];
    const float4 d3 = p1[i3];
    const float4 e0 = p2[lane];
    const float4 e1 = p2[lane + 64];
    const float4 e2 = p2[lane + 128];
    const float4 e3 = p2[i3];
    __builtin_amdgcn_sched_barrier(0);

    vfloat4 o;
    o.x = a0.x*w0 + d0.x*w1 + e0.x*w2;
    o.y = a0.y*w0 + d0.y*w1 + e0.y*w2;
    o.z = a0.z*w0 + d0.z*w1 + e0.z*w2;
    o.w = a0.w*w0 + d0.w*w1 + e0.w*w2;
    __builtin_nontemporal_store(o, &po[lane]);
    o.x = a1.x*w0 + d1.x*w1 + e1.x*w2;
    o.y = a1.y*w0 + d1.y*w1 + e1.y*w2;
    o.z = a1.z*w0 + d1.z*w1 + e1.z*w2;
    o.w = a1.w*w0 + d1.w*w1 + e1.w*w2;
    __builtin_nontemporal_store(o, &po[lane + 64]);
    o.x = a2.x*w0 + d2.x*w1 + e2.x*w2;
    o.y = a2.y*w0 + d2.y*w1 + e2.y*w2;
    o.z = a2.z*w0 + d2.z*w1 + e2.z*w2;
    o.w = a2.w*w0 + d2.w*w1 + e2.w*w2;
    __builtin_nontemporal_store(o, &po[lane + 128]);
    if (tail) {
        o.x = a3.x*w0 + d3.x*w1 + e3.x*w2;
        o.y = a3.y*w0 + d3.y*w1 + e3.y*w2;
        o.z = a3.z*w0 + d3.z*w1 + e3.z*w2;
        o.w = a3.w*w0 + d3.w*w1 + e3.w*w2;
        __builtin_nontemporal_store(o, &po[i3]);
    }
}

extern "C" void kernel_launch(void* const* d_in, const int* in_sizes, int n_in,
                              void* d_out, int out_size, void* d_ws, size_t ws_size,
                              hipStream_t stream) {
    const float* x0 = (const float*)d_in[0];
    const float* x1 = (const float*)d_in[1];
    const float* x2 = (const float*)d_in[2];
    const float* W1 = (const float*)d_in[3];
    const float* b1 = (const float*)d_in[4];
    const float* W2 = (const float*)d_in[5];
    const float* b2 = (const float*)d_in[6];
    float* out = (float*)d_out;

    float* stats = (float*)d_ws;                 // NB*TWOC floats
    float* hbuf  = stats + NB * TWOC;            // NB*NH floats
    float* wbuf  = hbuf + NB * NH;               // NB*3*NC floats

    stats_kernel<<<SWAVES / 4, 256, 0, stream>>>(x0, x1, x2, stats);
    h_kernel<<<2048, 256, 0, stream>>>(stats, W1, b1, hbuf);
    sw_kernel<<<2048, 256, 0, stream>>>(hbuf, W2, b2, wbuf);
    apply_kernel<<<NB * NC / 4, 256, 0, stream>>>(x0, x1, x2, wbuf, out);
}